// Round 2
// baseline (982.797 us; speedup 1.0000x reference)
//
#include <hip/hip_runtime.h>

// VQ nearest-codebook: argmin_k ||z_n - e_k||^2 over K=4096 codes, D=256.
// The np reference computes dists in fp32: (||z||^2 - 2 z.e^T) + ||e||^2 with
// ||z||^2 ~ 256 -> dists quantized at ulp(256)=3.05e-5; top-2 gaps ~1.9e-4 ->
// ~10% of rows have exact fp32 ties broken by argmin's first-index rule.
// So we REPLICATE the fp32 numerics: d = fp32(fp32(rn - 2*dot) + cn), with
// strict-< / lowest-index tie-breaking. Row-norm summation order is irrelevant
// (any fp32 rn differs from numpy's by an exact multiple of the grid ulp ->
// uniform shift, ties preserved); dot accumulation-order diffs vs BLAS are
// ~1.5e-10 vs the 3.05e-5 bucket -> ~0.5 expected flips (irreducible).
// Compute-bound: 68.7 GFLOP fp32 vector (no fp32 MFMA on CDNA4), 437us floor.

constexpr int Dc  = 256;
constexpr int Kc  = 4096;
constexpr int HWc = 1024;    // 32*32 (h*w), rows contiguous per d in NCHW
constexpr int BM  = 64;      // rows per block
constexpr int BN  = 128;     // codes per K-tile
constexpr int BKC = 32;      // d-chunk for B staging

// ||e_k||^2 prepass: one wave per code, coalesced float4 row read, shfl reduce.
__global__ __launch_bounds__(256) void vq_esq(const float* __restrict__ emb,
                                              float* __restrict__ E) {
  int wid  = (blockIdx.x * 256 + threadIdx.x) >> 6;   // global wave id == code id
  int lane = threadIdx.x & 63;
  float4 v = reinterpret_cast<const float4*>(emb + (size_t)wid * Dc)[lane];
  float s = v.x * v.x + v.y * v.y + v.z * v.z + v.w * v.w;
  #pragma unroll
  for (int off = 32; off > 0; off >>= 1) s += __shfl_down(s, off);
  if (lane == 0) E[wid] = s;
}

__global__ __launch_bounds__(256, 2) void vq_main(const float* __restrict__ z,
                                                  const float* __restrict__ emb,
                                                  const float* __restrict__ E,
                                                  int* __restrict__ out) {
  extern __shared__ float lds[];
  float* Az = lds;              // [256][64]  fp32, 64 KB, staged once
  float* Bs = lds + 256 * 64;   // [BKC][128] fp32, 16 KB, transposed B chunk

  const int t  = threadIdx.x;
  const int tn = t & 15;        // 16 code-groups
  const int tm = t >> 4;        // 16 row-groups of 4 rows
  const int r0 = blockIdx.x * BM;
  const int b  = r0 >> 10;          // batch index (1024 rows per image)
  const int hw0 = r0 & (HWc - 1);   // multiple of 64
  const float* zb = z + (size_t)b * Dc * HWc + hw0;  // A(d,m) = zb[d*1024 + m]

  // ---- stage A tile once: 256 d x 64 m = 4096 float4, 16 per thread, coalesced
  #pragma unroll
  for (int p = 0; p < 16; ++p) {
    int f  = t + p * 256;
    int dk = f >> 4, mq = f & 15;
    float4 a = *reinterpret_cast<const float4*>(zb + dk * HWc + mq * 4);
    *reinterpret_cast<float4*>(&Az[dk * 64 + mq * 4]) = a;
  }
  __syncthreads();

  // ---- per-thread row norms for this thread's 4 rows (16x redundant across tn,
  // 0.4% of total FMAs; LDS reads broadcast). fp32 order irrelevant (see header).
  float rn[4];
  #pragma unroll
  for (int r = 0; r < 4; ++r) {
    float s = 0.0f;
    for (int d = 0; d < Dc; ++d) {
      float a = Az[d * 64 + tm * 4 + r];
      s = fmaf(a, a, s);
    }
    rn[r] = s;
  }

  float best0[4] = {1e30f, 1e30f, 1e30f, 1e30f};
  float best1[4] = {1e30f, 1e30f, 1e30f, 1e30f};
  int   bidx0[4] = {0, 0, 0, 0};
  int   bidx1[4] = {0, 0, 0, 0};

  for (int kb = 0; kb < Kc; kb += BN) {
    float acc[4][8] = {};   // [row r][code q]; q<4 -> kb+tn*4+q, q>=4 -> kb+64+tn*4+(q-4)
    #pragma unroll 1
    for (int d0 = 0; d0 < Dc; d0 += BKC) {
      __syncthreads();   // Bs readers from previous chunk done
      // ---- stage B chunk transposed: Bs[dk][n] = emb[kb+n][d0+dk]; 1024 float4, 4/thread
      #pragma unroll
      for (int p = 0; p < 4; ++p) {
        int f = t + p * 256;
        int n = f >> 3, c = f & 7;
        float4 bq = *reinterpret_cast<const float4*>(emb + (size_t)(kb + n) * Dc + d0 + c * 4);
        Bs[(c * 4 + 0) * 128 + n] = bq.x;
        Bs[(c * 4 + 1) * 128 + n] = bq.y;
        Bs[(c * 4 + 2) * 128 + n] = bq.z;
        Bs[(c * 4 + 3) * 128 + n] = bq.w;
      }
      __syncthreads();
      // ---- inner product: 4 rows x 8 codes per thread, 32 FMA per dk
      #pragma unroll
      for (int dk = 0; dk < BKC; ++dk) {
        float4 av = *reinterpret_cast<const float4*>(&Az[(d0 + dk) * 64 + tm * 4]);
        float4 b0 = *reinterpret_cast<const float4*>(&Bs[dk * 128 + tn * 4]);
        float4 b1 = *reinterpret_cast<const float4*>(&Bs[dk * 128 + 64 + tn * 4]);
        float a4[4] = {av.x, av.y, av.z, av.w};
        float bb[8] = {b0.x, b0.y, b0.z, b0.w, b1.x, b1.y, b1.z, b1.w};
        #pragma unroll
        for (int r = 0; r < 4; ++r)
          #pragma unroll
          for (int q = 0; q < 8; ++q)
            acc[r][q] = fmaf(a4[r], bb[q], acc[r][q]);
      }
    }
    // ---- fold into running argmin, REPLICATING fp32 reference numerics:
    //   v = fp32(fp32(rn - 2*dot) + cn)   (one rounding per op, like numpy)
    // strict < over ascending k keeps first (lowest) index on exact ties.
    #pragma unroll
    for (int q = 0; q < 4; ++q) {
      int k0 = kb + tn * 4 + q;
      float e0 = E[k0];
      #pragma unroll
      for (int r = 0; r < 4; ++r) {
        float v = fmaf(-2.0f, acc[r][q], rn[r]) + e0;
        if (v < best0[r]) { best0[r] = v; bidx0[r] = k0; }
      }
      int k1 = kb + 64 + tn * 4 + q;
      float e1 = E[k1];
      #pragma unroll
      for (int r = 0; r < 4; ++r) {
        float v = fmaf(-2.0f, acc[r][q + 4], rn[r]) + e1;
        if (v < best1[r]) { best1[r] = v; bidx1[r] = k1; }
      }
    }
  }

  // ---- final reduce: merge two streams, then across the 16 tn lanes (lex (val,idx) min)
  #pragma unroll
  for (int r = 0; r < 4; ++r) {
    float bv = best0[r]; int bi = bidx0[r];
    if (best1[r] < bv || (best1[r] == bv && bidx1[r] < bi)) { bv = best1[r]; bi = bidx1[r]; }
    #pragma unroll
    for (int off = 1; off < 16; off <<= 1) {
      float ov = __shfl_xor(bv, off);
      int   oi = __shfl_xor(bi, off);
      if (ov < bv || (ov == bv && oi < bi)) { bv = ov; bi = oi; }
    }
    if (tn == 0) out[r0 + tm * 4 + r] = bi;
  }
}

extern "C" void kernel_launch(void* const* d_in, const int* in_sizes, int n_in,
                              void* d_out, int out_size, void* d_ws, size_t ws_size,
                              hipStream_t stream) {
  const float* z   = (const float*)d_in[0];   // [32,256,32,32]
  const float* emb = (const float*)d_in[1];   // [4096,256]
  int*   out = (int*)d_out;                   // [32,32,32] int32 indices
  float* E   = (float*)d_ws;                  // [4096] ||e_k||^2

  // prepass: 4096 waves = 1024 blocks x 256 threads
  vq_esq<<<Kc / 4, 256, 0, stream>>>(emb, E);

  // main: 512 blocks x 256 threads, 80 KB dynamic LDS
  const size_t lds_bytes = (256 * 64 + BKC * 128) * sizeof(float);  // 81920
  (void)hipFuncSetAttribute((const void*)vq_main,
                            hipFuncAttributeMaxDynamicSharedMemorySize,
                            (int)lds_bytes);
  vq_main<<<32768 / BM, 256, lds_bytes, stream>>>(z, emb, E, out);
}

// Round 6
// 925.411 us; speedup vs baseline: 1.0620x; 1.0620x over previous
//
#include <hip/hip_runtime.h>

// VQ nearest-codebook: argmin_k ||z_n - e_k||^2, N=32768 rows (D=256), K=4096.
// Replicates the np/BLAS fp32 numerics: d = fp32(fp32(rn - 2*dot) + cn), dot
// accumulated sequentially over d (matches round-2 kernel which scored absmax=0);
// strict-< ascending-k argmin reproduces first-index tie-breaking on the
// ulp(256)=3.05e-5 grid. Compute-bound fp32 vector GEMM (no fp32 MFMA): 437us floor.
//
// Round-3 changes vs round-2 (982us, VALUBusy 56%, LDS_BANK_CONFLICT 1.17e8):
//  * T2: XOR-swizzled Bs layout at float4 granularity:
//      (dk,n) -> Bs[dk*128 + ((n>>2 ^ dk>>2)<<2) + (n&3)]
//    staging writes go 8-way -> 2-way (free); reads stay float4 + <=2-way.
//  * T14: next B-chunk prefetched global->reg during compute, reg->LDS after
//    the barrier (hides L2 latency; 2 blocks/CU can't cover it alone).

constexpr int Dc  = 256;
constexpr int Kc  = 4096;
constexpr int HWc = 1024;    // 32*32 rows contiguous per d (NCHW)
constexpr int BM  = 64;      // rows per block
constexpr int BN  = 128;     // codes per K-tile
constexpr int BKC = 32;      // d-chunk
constexpr int NCHUNK = (Kc / BN) * (Dc / BKC);   // 256 staging chunks

// ||e_k||^2 prepass: one wave per code, coalesced float4 row read, shfl reduce.
__global__ __launch_bounds__(256) void vq_esq(const float* __restrict__ emb,
                                              float* __restrict__ E) {
  int wid  = (blockIdx.x * 256 + threadIdx.x) >> 6;
  int lane = threadIdx.x & 63;
  float4 v = reinterpret_cast<const float4*>(emb + (size_t)wid * Dc)[lane];
  float s = v.x * v.x + v.y * v.y + v.z * v.z + v.w * v.w;
  #pragma unroll
  for (int off = 32; off > 0; off >>= 1) s += __shfl_down(s, off);
  if (lane == 0) E[wid] = s;
}

__global__ __launch_bounds__(256, 2) void vq_main(const float* __restrict__ z,
                                                  const float* __restrict__ emb,
                                                  const float* __restrict__ E,
                                                  int* __restrict__ out) {
  extern __shared__ float lds[];
  float* Az = lds;              // [256][64] fp32, 64 KB, staged once
  float* Bs = lds + 256 * 64;   // [32][128] fp32 swizzled, 16 KB

  const int t  = threadIdx.x;
  const int tn = t & 15;        // 16 code-groups
  const int tm = t >> 4;        // 16 row-groups of 4 rows
  const int r0 = blockIdx.x * BM;
  const int b  = r0 >> 10;
  const int hw0 = r0 & (HWc - 1);
  const float* zb = z + (size_t)b * Dc * HWc + hw0;   // A(d,m) = zb[d*1024+m]

  // B-staging thread geometry (same for every chunk):
  //   lane handles rows n = nb + 32p (p=0..3), columns cg*4..cg*4+3 of the chunk
  const int cg  = t & 7;
  const int nb  = t >> 3;          // [0,32)
  const int n4b = nb >> 2;         // [0,8)
  const int nl  = nb & 3;

  // ---- stage A tile once: 4096 float4, 16/thread, coalesced
  #pragma unroll
  for (int p = 0; p < 16; ++p) {
    int f  = t + p * 256;
    int dk = f >> 4, mq = f & 15;
    float4 a = *reinterpret_cast<const float4*>(zb + dk * HWc + mq * 4);
    *reinterpret_cast<float4*>(&Az[dk * 64 + mq * 4]) = a;
  }

  // ---- T14 prefetch: chunk 0 (kb=0,d0=0) global->reg while Az settles
  float4 rr[4];
  {
    const float* base = emb + (size_t)0 * Dc + 0 + cg * 4;
    #pragma unroll
    for (int p = 0; p < 4; ++p)
      rr[p] = *reinterpret_cast<const float4*>(base + (size_t)(nb + 32 * p) * Dc);
  }

  __syncthreads();   // Az visible

  // ---- per-thread row norms (fp32, order-robust vs numpy: uniform grid shift)
  float rn[4];
  #pragma unroll
  for (int r = 0; r < 4; ++r) {
    float s = 0.0f;
    for (int d = 0; d < Dc; ++d) {
      float a = Az[d * 64 + tm * 4 + r];
      s = fmaf(a, a, s);
    }
    rn[r] = s;
  }

  float best0[4] = {1e30f, 1e30f, 1e30f, 1e30f};
  float best1[4] = {1e30f, 1e30f, 1e30f, 1e30f};
  int   bidx0[4] = {0, 0, 0, 0};
  int   bidx1[4] = {0, 0, 0, 0};

  int ci = 0;   // flat chunk index = (kb/BN)*8 + d0/BKC
  for (int kb = 0; kb < Kc; kb += BN) {
    float acc[4][8] = {};
    #pragma unroll 1
    for (int d0 = 0; d0 < Dc; d0 += BKC) {
      __syncthreads();   // previous chunk's readers done
      // ---- reg -> LDS, swizzled: element (dk,n) at dk*128 + ((n4^(dk>>2))<<2)+nl
      // rows dk = cg*4+j, n = nb+32p -> n4 = n4b+8p, col slot = (8p+(n4b^cg))*4+nl
      #pragma unroll
      for (int p = 0; p < 4; ++p) {
        int col = ((8 * p + (n4b ^ cg)) << 2) + nl;
        Bs[(cg * 4 + 0) * 128 + col] = rr[p].x;
        Bs[(cg * 4 + 1) * 128 + col] = rr[p].y;
        Bs[(cg * 4 + 2) * 128 + col] = rr[p].z;
        Bs[(cg * 4 + 3) * 128 + col] = rr[p].w;
      }
      // ---- issue next chunk's global loads (landing during compute below)
      float4 rn_[4];
      if (ci + 1 < NCHUNK) {
        int kbn = ((ci + 1) >> 3) * BN;
        int d0n = ((ci + 1) & 7) * BKC;
        const float* base = emb + (size_t)kbn * Dc + d0n + cg * 4;
        #pragma unroll
        for (int p = 0; p < 4; ++p)
          rn_[p] = *reinterpret_cast<const float4*>(base + (size_t)(nb + 32 * p) * Dc);
      }
      __syncthreads();   // Bs ready
      // ---- inner product: 4 rows x 8 codes per thread, 32 FMA per dk
      #pragma unroll
      for (int dk = 0; dk < BKC; ++dk) {
        const int c = dk >> 2;
        float4 av = *reinterpret_cast<const float4*>(&Az[(d0 + dk) * 64 + tm * 4]);
        float4 b0 = *reinterpret_cast<const float4*>(&Bs[dk * 128 + ((tn ^ c) << 2)]);
        float4 b1 = *reinterpret_cast<const float4*>(&Bs[dk * 128 + (((16 + tn) ^ c) << 2)]);
        float a4[4] = {av.x, av.y, av.z, av.w};
        float bb[8] = {b0.x, b0.y, b0.z, b0.w, b1.x, b1.y, b1.z, b1.w};
        #pragma unroll
        for (int r = 0; r < 4; ++r)
          #pragma unroll
          for (int q = 0; q < 8; ++q)
            acc[r][q] = fmaf(a4[r], bb[q], acc[r][q]);
      }
      #pragma unroll
      for (int p = 0; p < 4; ++p) rr[p] = rn_[p];
      ++ci;
    }
    // ---- fold into running argmin, replicating fp32 reference numerics:
    //   v = fp32(fp32(rn - 2*dot) + cn); strict < over ascending k keeps first index
    #pragma unroll
    for (int q = 0; q < 4; ++q) {
      int k0 = kb + tn * 4 + q;
      float e0 = E[k0];
      #pragma unroll
      for (int r = 0; r < 4; ++r) {
        float v = fmaf(-2.0f, acc[r][q], rn[r]) + e0;
        if (v < best0[r]) { best0[r] = v; bidx0[r] = k0; }
      }
      int k1 = kb + 64 + tn * 4 + q;
      float e1 = E[k1];
      #pragma unroll
      for (int r = 0; r < 4; ++r) {
        float v = fmaf(-2.0f, acc[r][q + 4], rn[r]) + e1;
        if (v < best1[r]) { best1[r] = v; bidx1[r] = k1; }
      }
    }
  }

  // ---- final reduce: merge streams, then across 16 tn lanes (lex (val,idx) min)
  #pragma unroll
  for (int r = 0; r < 4; ++r) {
    float bv = best0[r]; int bi = bidx0[r];
    if (best1[r] < bv || (best1[r] == bv && bidx1[r] < bi)) { bv = best1[r]; bi = bidx1[r]; }
    #pragma unroll
    for (int off = 1; off < 16; off <<= 1) {
      float ov = __shfl_xor(bv, off);
      int   oi = __shfl_xor(bi, off);
      if (ov < bv || (ov == bv && oi < bi)) { bv = ov; bi = oi; }
    }
    if (tn == 0) out[r0 + tm * 4 + r] = bi;
  }
}

extern "C" void kernel_launch(void* const* d_in, const int* in_sizes, int n_in,
                              void* d_out, int out_size, void* d_ws, size_t ws_size,
                              hipStream_t stream) {
  const float* z   = (const float*)d_in[0];   // [32,256,32,32]
  const float* emb = (const float*)d_in[1];   // [4096,256]
  int*   out = (int*)d_out;                   // [32,32,32]
  float* E   = (float*)d_ws;                  // [4096] ||e_k||^2

  vq_esq<<<Kc / 4, 256, 0, stream>>>(emb, E);

  const size_t lds_bytes = (256 * 64 + BKC * 128) * sizeof(float);  // 81920
  (void)hipFuncSetAttribute((const void*)vq_main,
                            hipFuncAttributeMaxDynamicSharedMemorySize,
                            (int)lds_bytes);
  vq_main<<<32768 / BM, 256, lds_bytes, stream>>>(z, emb, E, out);
}